// Round 18
// baseline (281.059 us; speedup 1.0000x reference)
//
#include <hip/hip_runtime.h>

typedef unsigned short u16;
typedef u16   u16x4  __attribute__((ext_vector_type(4)));
typedef u16   u16x8  __attribute__((ext_vector_type(8)));
typedef short short8 __attribute__((ext_vector_type(8)));
typedef float floatx4 __attribute__((ext_vector_type(4)));
typedef float f4     __attribute__((ext_vector_type(4)));

typedef const __attribute__((address_space(1))) unsigned gu32;
typedef __attribute__((address_space(3))) unsigned lu32;

#define BB 8
#define NN 4096
#define CC 384

__device__ __forceinline__ u16 f2bf(float f){
  unsigned u = __float_as_uint(f);
  u += 0x7FFFu + ((u >> 16) & 1u);   // round-to-nearest-even
  return (u16)(u >> 16);
}

// ---------------- Kernel A: conv+LN+GELU+residual  ∪  WT transpose  ∪  zero(S,ctx) --------------
// grid 4302 x 384thr: [0,4096) conv pixels; [4096,4204) WT prep; [4204,4302) zero 98x6144B.
__global__ __launch_bounds__(384) void k_pre(
    const float* __restrict__ x, const float* __restrict__ w_sr, const float* __restrict__ b_sr,
    const float* __restrict__ ln_g, const float* __restrict__ ln_b,
    const float* __restrict__ wqkv, u16* __restrict__ xa16, u16* __restrict__ WT,
    float* __restrict__ Z)
{
  const int blk = blockIdx.x;

  if (blk >= 4204) {                    // ---- zero S+ctx: 602112 B total ----
    int off = (blk - 4204) * 1536 + ((int)threadIdx.x << 2);
    const f4 zz = {0.f, 0.f, 0.f, 0.f};
    *(f4*)(Z + off) = zz;
    return;
  }

  if (blk >= 4096) {                    // ---- WT[col][k] = bf16(wqkv[k][col]) ----
    const int pb = blk - 4096;
    const int cg = pb % 18, kg = pb / 18;
    const int c0 = cg << 6, k0 = kg << 6;
    const int tid = threadIdx.x;
    __shared__ u16 t[64][72];
    if (tid < 256) {
#pragma unroll
      for (int i = 0; i < 4; i++) {
        int idx = tid + (i << 8);
        int r = idx >> 4, c4 = (idx & 15) << 2;
        f4 v = *(const f4*)(wqkv + (size_t)(k0 + r) * 1152 + c0 + c4);
#pragma unroll
        for (int j = 0; j < 4; j++) t[c4 + j][r] = f2bf(v[j]);
      }
    }
    __syncthreads();
    if (tid < 256) {
#pragma unroll
      for (int i = 0; i < 2; i++) {
        int idx = tid + (i << 8);
        int c = idx >> 3, j = (idx & 7) << 3;
        *(u16x8*)(WT + (size_t)(c0 + c) * 384 + k0 + j) = *(const u16x8*)&t[c][j];
      }
    }
    return;
  }

  // ---- conv path (verbatim R3-R17) ----
  const int b = blk >> 9;
  const int hh = (blk >> 3) & 63;
  const int ww0 = (blk & 7) << 3;
  const int c = threadIdx.x;

  float wgt[9];
#pragma unroll
  for (int i = 0; i < 9; i++) wgt[i] = w_sr[c * 9 + i];
  const float lg = ln_g[c], lb = ln_b[c];
  const float bias = b_sr[c];

  float rowv[3][10];
#pragma unroll
  for (int r = 0; r < 3; r++) {
    int y = hh + r - 1;
    bool yok = (unsigned)y < 64u;
#pragma unroll
    for (int j = 0; j < 10; j++) {
      int xx = ww0 + j - 1;
      bool ok = yok && ((unsigned)xx < 64u);
      rowv[r][j] = ok ? x[((size_t)((b << 12) + (y << 6) + xx)) * CC + c] : 0.f;
    }
  }

  float acc[8];
#pragma unroll
  for (int p = 0; p < 8; p++) {
    float a = bias;
#pragma unroll
    for (int r = 0; r < 3; r++)
#pragma unroll
      for (int j = 0; j < 3; j++)
        a += rowv[r][p + j] * wgt[r * 3 + j];
    acc[p] = a;
  }

  __shared__ float ls1[6][8], ls2[6][8], mb[2][8];
  const int wid = threadIdx.x >> 6, lane = threadIdx.x & 63;
#pragma unroll
  for (int p = 0; p < 8; p++) {
    float s1 = acc[p], s2 = acc[p] * acc[p];
#pragma unroll
    for (int o = 32; o > 0; o >>= 1) { s1 += __shfl_down(s1, o); s2 += __shfl_down(s2, o); }
    if (lane == 0) { ls1[wid][p] = s1; ls2[wid][p] = s2; }
  }
  __syncthreads();
  if (threadIdx.x < 8) {
    int p = threadIdx.x;
    float a = 0.f, q = 0.f;
#pragma unroll
    for (int i = 0; i < 6; i++) { a += ls1[i][p]; q += ls2[i][p]; }
    float mean = a * (1.0f / CC);
    float var  = q * (1.0f / CC) - mean * mean;
    mb[0][p] = mean; mb[1][p] = rsqrtf(var + 1e-5f);
  }
  __syncthreads();
#pragma unroll
  for (int p = 0; p < 8; p++) {
    float xn = (acc[p] - mb[0][p]) * mb[1][p] * lg + lb;
    float g  = 0.5f * xn * (1.0f + erff(xn * 0.70710678118654752f));
    size_t pix = (size_t)(b << 12) + (hh << 6) + ww0 + p;
    xa16[pix * CC + c] = f2bf(rowv[1][p + 1] + g);
  }
}

// ---------------- Kernel B: merged qkv GEMM — A via dbuf DMA, B DIRECT from L2 ------------------
// XCD-coherent interleaved grid (R17, verified: FETCH at floor). B-tile is block-invariant and
// L2-resident -> LDS staging of B was pure overhead (57KB -> 8.2KB; occupancy-bound no more).
// bf[3] fragments read straight from WT inside compute; TLP at ~2x occupancy covers L2 latency.
__global__ __launch_bounds__(512) void k_qkv(
    const u16* __restrict__ xa16, const u16* __restrict__ WT, float* __restrict__ S,
    u16* __restrict__ K16T, u16* __restrict__ V16T, u16* __restrict__ P16)
{
  const int bid = blockIdx.x;           // 0..1535 = 24 * 64
  const int G   = bid / 24;
  const int w24 = bid - G * 24;
  const int g   = w24 >> 3;             // 0=k, 1=v, 2=q
  const int rt  = (G << 3) + (w24 & 7); // rowtile of 64
  const int b  = rt >> 6;
  const int n0 = rt << 6;
  const int tid = threadIdx.x;
  const int wv = tid >> 6, lane = tid & 63, l15 = lane & 15, quad = lane >> 4;
  const int wc = wv;

  __shared__ __attribute__((aligned(16))) u16 lA[2][64][32];

  const u16* Bbase = WT + (size_t)((g == 2) ? 0 : (384 + g * 384)) * 384;
  const int sw8 = (quad ^ ((l15 >> 1) & 3)) << 3;

  floatx4 acc[12];
  const floatx4 z = {0.f, 0.f, 0.f, 0.f};
#pragma unroll
  for (int i = 0; i < 12; i++) acc[i] = z;

  // stage A 64x32 tile into buffer bi (1 DMA inst per wave, waves 0..3 only)
  auto stageA = [&](int bi, int k0) {
    if (wv < 4) {
      int cl = (wv << 4) + (lane >> 2);
      int sc = ((lane & 3) ^ ((cl >> 1) & 3)) << 3;
      __builtin_amdgcn_global_load_lds((gu32*)(xa16 + (size_t)(n0 + cl) * 384 + k0 + sc),
                                       (lu32*)&lA[bi][wv << 4][0], 16, 0, 0);
    }
  };

  // per-wave B fragment base: rows (wc*48 + ni*16 + l15) of Bbase, k-contiguous
  const u16* Brow0 = Bbase + (size_t)(wc * 48 +  0 + l15) * 384 + (quad << 3);
  const u16* Brow1 = Bbase + (size_t)(wc * 48 + 16 + l15) * 384 + (quad << 3);
  const u16* Brow2 = Bbase + (size_t)(wc * 48 + 32 + l15) * 384 + (quad << 3);

  stageA(0, 0);

  for (int t = 0; t < 12; t++) {
    const int cur = t & 1;
    if (t < 11) {
      stageA(cur ^ 1, (t + 1) << 5);
      // wv<4: outstanding = A_cur + A_nxt -> wait vmcnt(1) so A_cur has landed, A_nxt in flight.
      // (bf loads from previous step completed before their MFMAs; none outstanding here.)
      if (wv < 4) asm volatile("s_waitcnt vmcnt(1)" ::: "memory");
    } else {
      if (wv < 4) asm volatile("s_waitcnt vmcnt(0)" ::: "memory");
    }
    __builtin_amdgcn_s_barrier();       // all waves see completed lA[cur]
    const int kof = t << 5;
    short8 bf[3];
    bf[0] = *(const short8*)(Brow0 + kof);
    bf[1] = *(const short8*)(Brow1 + kof);
    bf[2] = *(const short8*)(Brow2 + kof);
    short8 af[4];
#pragma unroll
    for (int mi = 0; mi < 4; mi++) af[mi] = *(const short8*)&lA[cur][(mi << 4) + l15][sw8];
#pragma unroll
    for (int mi = 0; mi < 4; mi++)
#pragma unroll
      for (int ni = 0; ni < 3; ni++)
        acc[mi * 3 + ni] = __builtin_amdgcn_mfma_f32_16x16x32_bf16(af[mi], bf[ni], acc[mi * 3 + ni], 0, 0, 0);
    __builtin_amdgcn_s_barrier();       // reads of lA[cur] done before anyone re-stages it
  }

  if (g == 0) {
    // per-row softmax over this wave's head (48 cols = 3 regs x 16 l15 lanes)
#pragma unroll
    for (int mi = 0; mi < 4; mi++)
#pragma unroll
      for (int rr = 0; rr < 4; rr++) {
        float x0 = acc[mi * 3 + 0][rr], x1 = acc[mi * 3 + 1][rr], x2 = acc[mi * 3 + 2][rr];
        float m = fmaxf(fmaxf(x0, x1), x2);
#pragma unroll
        for (int o = 8; o >= 1; o >>= 1) m = fmaxf(m, __shfl_xor(m, o));
        float e0 = expf(x0 - m), e1 = expf(x1 - m), e2 = expf(x2 - m);
        float s = e0 + e1 + e2;
#pragma unroll
        for (int o = 8; o >= 1; o >>= 1) s += __shfl_xor(s, o);
        float inv = 1.0f / s;
        acc[mi * 3 + 0][rr] = e0 * inv; acc[mi * 3 + 1][rr] = e1 * inv; acc[mi * 3 + 2][rr] = e2 * inv;
      }
  }

  if (g == 2) {
    // q epilogue: exp -> P16 + column sums
#pragma unroll
    for (int ni = 0; ni < 3; ni++) {
      int col = wc * 48 + (ni << 4) + l15;
      float s = 0.f;
#pragma unroll
      for (int mi = 0; mi < 4; mi++) {
        int rowb = n0 + (mi << 4) + (quad << 2);
        float e0 = expf(acc[mi * 3 + ni][0]), e1 = expf(acc[mi * 3 + ni][1]);
        float e2 = expf(acc[mi * 3 + ni][2]), e3 = expf(acc[mi * 3 + ni][3]);
        P16[(size_t)(rowb + 0) * 384 + col] = f2bf(e0);
        P16[(size_t)(rowb + 1) * 384 + col] = f2bf(e1);
        P16[(size_t)(rowb + 2) * 384 + col] = f2bf(e2);
        P16[(size_t)(rowb + 3) * 384 + col] = f2bf(e3);
        s += e0 + e1 + e2 + e3;
      }
      s += __shfl_down(s, 32);
      s += __shfl_down(s, 16);
      if (lane < 16) atomicAdd(&S[b * 384 + wc * 48 + (ni << 4) + lane], s);
    }
  } else {
    u16* dst = g ? V16T : K16T;
    const int nl = ((rt & 63) << 6) + (quad << 2);
#pragma unroll
    for (int mi = 0; mi < 4; mi++)
#pragma unroll
      for (int ni = 0; ni < 3; ni++) {
        int hd = wc * 48 + (ni << 4) + l15;
        u16x4 v4 = { f2bf(acc[mi * 3 + ni][0]), f2bf(acc[mi * 3 + ni][1]),
                     f2bf(acc[mi * 3 + ni][2]), f2bf(acc[mi * 3 + ni][3]) };
        *(u16x4*)(dst + ((size_t)b * 384 + hd) * 4096 + nl + (mi << 4)) = v4;
      }
  }
}

// ---------------- Kernel C: ctx[bh,48,48] += ksm^T @ v over 256-row n-chunks (MFMA) -------------
__global__ __launch_bounds__(256) void k_ctx(
    const u16* __restrict__ K16T, const u16* __restrict__ V16T, float* __restrict__ ctx)
{
  const int bh = blockIdx.x;           // 64
  const int b = bh >> 3, h = bh & 7;
  const int n0 = blockIdx.y << 8;      // chunk of 256 n
  const int tid = threadIdx.x;
  const int wv = tid >> 6, lane = tid & 63, l15 = lane & 15, quad = lane >> 4;

  __shared__ __attribute__((aligned(16))) char smem[50688];
  u16 (*lkT)[264] = (u16(*)[264])smem;             // 48 x 264 (ksm^T: [d][n])
  u16 (*lvT)[264] = (u16(*)[264])(smem + 25344);   // 48 x 264 (v^T:   [e][n])
  float (*pctx)[2304] = (float(*)[2304])smem;      // 4 x 2304 (overlaps, used after barrier)

#pragma unroll
  for (int i = 0; i < 6; i++) {
    int idx = tid + (i << 8);          // 0..1535
    int d = idx >> 5, c8 = (idx & 31) << 3;
    *(u16x8*)&lkT[d][c8] = *(const u16x8*)(K16T + ((size_t)b * 384 + h * 48 + d) * 4096 + n0 + c8);
    *(u16x8*)&lvT[d][c8] = *(const u16x8*)(V16T + ((size_t)b * 384 + h * 48 + d) * 4096 + n0 + c8);
  }
  __syncthreads();

  floatx4 c2[9];
  const floatx4 z = {0.f, 0.f, 0.f, 0.f};
#pragma unroll
  for (int i = 0; i < 9; i++) c2[i] = z;
#pragma unroll
  for (int kk2 = 0; kk2 < 2; kk2++) {
    int rb = (wv << 6) + (kk2 << 5) + (quad << 3);
    short8 ak[3], av[3];
#pragma unroll
    for (int t = 0; t < 3; t++) {
      ak[t] = *(const short8*)&lkT[(t << 4) + l15][rb];
      av[t] = *(const short8*)&lvT[(t << 4) + l15][rb];
    }
#pragma unroll
    for (int dt = 0; dt < 3; dt++)
#pragma unroll
      for (int et = 0; et < 3; et++)
        c2[dt * 3 + et] = __builtin_amdgcn_mfma_f32_16x16x32_bf16(ak[dt], av[et], c2[dt * 3 + et], 0, 0, 0);
  }
  __syncthreads();   // done reading lkT/lvT; smem reused as pctx

#pragma unroll
  for (int dt = 0; dt < 3; dt++)
#pragma unroll
    for (int et = 0; et < 3; et++)
#pragma unroll
      for (int rr = 0; rr < 4; rr++) {
        int d = (dt << 4) + (quad << 2) + rr;
        int e = (et << 4) + l15;
        pctx[wv][d * 48 + e] = c2[dt * 3 + et][rr];
      }
  __syncthreads();
#pragma unroll
  for (int i = 0; i < 9; i++) {
    int cell = tid + (i << 8);
    float s = pctx[0][cell] + pctx[1][cell] + pctx[2][cell] + pctx[3][cell];
    atomicAdd(&ctx[(size_t)bh * 2304 + cell], s);
  }
}

// ---------------- Kernel D: W2T[b, c, h*48+d] = sum_e (ctx[bh,d,e]/S[..]) * wp[h*48+e, c] -------
__global__ __launch_bounds__(256) void k_w2(
    const float* __restrict__ ctx, const float* __restrict__ S,
    const float* __restrict__ wp, u16* __restrict__ W2T)
{
  const int bh = blockIdx.x;   // 64
  const int b = bh >> 3, h = bh & 7;
  const int c0 = blockIdx.y << 7;
  const int tid = threadIdx.x;
  __shared__ float rs[48];
  __shared__ float c2[48][48];
  __shared__ float lwp[48][128];
  __shared__ u16 tr[128][48];
  if (tid < 48) rs[tid] = 1.0f / S[b * 384 + h * 48 + tid];
  __syncthreads();
#pragma unroll
  for (int i = 0; i < 9; i++) {
    int cell = tid + (i << 8);
    int d = cell / 48, e = cell - d * 48;
    c2[d][e] = ctx[(size_t)bh * 2304 + cell] * rs[d];
  }
#pragma unroll
  for (int i = 0; i < 24; i++) {
    int idx = tid + (i << 8);            // 0..6143
    int e = idx >> 7, c = idx & 127;
    lwp[e][c] = wp[(size_t)(h * 48 + e) * 384 + c0 + c];
  }
  __syncthreads();
  const int c = tid & 127;
  const int dbase = tid >> 7;            // 0 or 1
#pragma unroll
  for (int it = 0; it < 24; it++) {
    int d = (it << 1) + dbase;
    float s = 0.f;
#pragma unroll
    for (int e = 0; e < 48; e++) s += c2[d][e] * lwp[e][c];
    tr[c][d] = f2bf(s);
  }
  __syncthreads();
  const int cc = tid >> 1, half = tid & 1;
#pragma unroll
  for (int i = 0; i < 3; i++) {
    u16x8 v = *(const u16x8*)&tr[cc][half * 24 + (i << 3)];
    *(u16x8*)(W2T + ((size_t)b * 384 + c0 + cc) * 384 + h * 48 + half * 24 + (i << 3)) = v;
  }
}

// ---------------- Kernel E: out = P @ W2_b + bias + x  (async template + counted vmcnt) ---------
__global__ __launch_bounds__(512) void k_qproj(
    const u16* __restrict__ P16, const u16* __restrict__ W2T,
    const float* __restrict__ bias, const float* __restrict__ x, float* __restrict__ out)
{
  const int bm = blockIdx.x;            // 512 rowtiles of 64
  const int b = bm >> 6;
  const int n0 = bm << 6;
  const int tid = threadIdx.x;
  const int wv = tid >> 6, lane = tid & 63, l15 = lane & 15, quad = lane >> 4;
  const int wc = wv;

  __shared__ __attribute__((aligned(16))) u16 lA[2][64][32];
  __shared__ __attribute__((aligned(16))) u16 lB[2][384][32];

  const u16* Bbase = W2T + (size_t)b * 384 * 384;
  const int sw8 = (quad ^ ((l15 >> 1) & 3)) << 3;

  floatx4 acc[12];
  const floatx4 z = {0.f, 0.f, 0.f, 0.f};
#pragma unroll
  for (int i = 0; i < 12; i++) acc[i] = z;

  auto stage = [&](int bi, int k0) {
    if (wv < 4) {
      int cl = (wv << 4) + (lane >> 2);
      int sc = ((lane & 3) ^ ((cl >> 1) & 3)) << 3;
      __builtin_amdgcn_global_load_lds((gu32*)(P16 + (size_t)(n0 + cl) * 384 + k0 + sc),
                                       (lu32*)&lA[bi][wv << 4][0], 16, 0, 0);
    }
#pragma unroll
    for (int i = 0; i < 3; i++) {
      int j = wv * 3 + i;
      int cl = (j << 4) + (lane >> 2);
      int sc = ((lane & 3) ^ ((cl >> 1) & 3)) << 3;
      __builtin_amdgcn_global_load_lds((gu32*)(Bbase + (size_t)cl * 384 + k0 + sc),
                                       (lu32*)&lB[bi][j << 4][0], 16, 0, 0);
    }
  };

  stage(0, 0);

  for (int t = 0; t < 12; t++) {
    const int cur = t & 1;
    if (t < 11) {
      stage(cur ^ 1, (t + 1) << 5);
      if (wv < 4) asm volatile("s_waitcnt vmcnt(4)" ::: "memory");
      else        asm volatile("s_waitcnt vmcnt(3)" ::: "memory");
    } else {
      asm volatile("s_waitcnt vmcnt(0)" ::: "memory");
    }
    __builtin_amdgcn_s_barrier();
    short8 af[4], bf[3];
#pragma unroll
    for (int mi = 0; mi < 4; mi++) af[mi] = *(const short8*)&lA[cur][(mi << 4) + l15][sw8];
#pragma unroll
    for (int ni = 0; ni < 3; ni++) bf[ni] = *(const short8*)&lB[cur][wc * 48 + (ni << 4) + l15][sw8];
#pragma unroll
    for (int mi = 0; mi < 4; mi++)
#pragma unroll
      for (int ni = 0; ni < 3; ni++)
        acc[mi * 3 + ni] = __builtin_amdgcn_mfma_f32_16x16x32_bf16(af[mi], bf[ni], acc[mi * 3 + ni], 0, 0, 0);
    __builtin_amdgcn_s_barrier();
  }

#pragma unroll
  for (int ni = 0; ni < 3; ni++) {
    int col = wc * 48 + (ni << 4) + l15;
    float bc = bias[col];
#pragma unroll
    for (int mi = 0; mi < 4; mi++) {
#pragma unroll
      for (int rr = 0; rr < 4; rr++) {
        int row = n0 + (mi << 4) + (quad << 2) + rr;
        out[(size_t)row * 384 + col] = acc[mi * 3 + ni][rr] + bc + x[(size_t)row * 384 + col];
      }
    }
  }
}

extern "C" void kernel_launch(void* const* d_in, const int* in_sizes, int n_in,
                              void* d_out, int out_size, void* d_ws, size_t ws_size,
                              hipStream_t stream)
{
  const float* x      = (const float*)d_in[0];
  const float* w_sr   = (const float*)d_in[1];
  const float* b_sr   = (const float*)d_in[2];
  const float* ln_g   = (const float*)d_in[3];
  const float* ln_b   = (const float*)d_in[4];
  const float* w_qkv  = (const float*)d_in[5];
  const float* w_proj = (const float*)d_in[6];
  const float* b_proj = (const float*)d_in[7];
  float* out = (float*)d_out;

  // ws layout — total 54,177,792 bytes (~54.2 MB):
  //   [0,        12288)     S    [8][384] f32      (zeroed by k_pre)
  //   [12288,    602112)    ctx  [64][48][48] f32  (zeroed by k_pre)
  //   [602112,   1486848)   WT   [1152][384] bf16
  //   [1486848,  3846144)   W2T  [8][384][384] bf16
  //   [3846144,  29011968)  xa16 [32768][384] bf16
  //   [29011968, 54177792)  P16  [32768][384] bf16
  // d_out (50.3 MB) doubles as scratch for K16T+V16T (2 x 25.17 MB) until k_qproj writes it.
  float* S   = (float*)d_ws;
  float* ctx = (float*)((char*)d_ws + 12288);
  u16*   WT  = (u16*)((char*)d_ws + 602112);
  u16*   W2T = (u16*)((char*)d_ws + 1486848);
  u16*   xa16= (u16*)((char*)d_ws + 3846144);
  u16*   P16 = (u16*)((char*)d_ws + 29011968);
  u16*   K16T= (u16*)d_out;              // [8][384][4096] bf16
  u16*   V16T= (u16*)d_out + (size_t)8 * 384 * 4096;

  k_pre<<<4302, 384, 0, stream>>>(x, w_sr, b_sr, ln_g, ln_b, w_qkv, xa16, WT, (float*)d_ws);
  k_qkv<<<1536, 512, 0, stream>>>(xa16, WT, S, K16T, V16T, P16);
  k_ctx<<<dim3(64, 16), 256, 0, stream>>>(K16T, V16T, ctx);
  k_w2<<<dim3(64, 3), 256, 0, stream>>>(ctx, S, w_proj, W2T);
  k_qproj<<<512, 512, 0, stream>>>(P16, W2T, b_proj, x, out);
}

// Round 19
// 253.347 us; speedup vs baseline: 1.1094x; 1.1094x over previous
//
#include <hip/hip_runtime.h>

typedef unsigned short u16;
typedef u16   u16x4  __attribute__((ext_vector_type(4)));
typedef u16   u16x8  __attribute__((ext_vector_type(8)));
typedef short short8 __attribute__((ext_vector_type(8)));
typedef float floatx4 __attribute__((ext_vector_type(4)));
typedef float f4     __attribute__((ext_vector_type(4)));

typedef const __attribute__((address_space(1))) unsigned gu32;
typedef __attribute__((address_space(3))) unsigned lu32;

#define BB 8
#define NN 4096
#define CC 384

__device__ __forceinline__ u16 f2bf(float f){
  unsigned u = __float_as_uint(f);
  u += 0x7FFFu + ((u >> 16) & 1u);   // round-to-nearest-even
  return (u16)(u >> 16);
}

// ---------------- Kernel A: conv+LN+GELU+residual  ∪  WT transpose  ∪  zero(S,ctx) --------------
// grid 4302 x 384thr: [0,4096) conv pixels; [4096,4204) WT prep; [4204,4302) zero 98x6144B.
__global__ __launch_bounds__(384) void k_pre(
    const float* __restrict__ x, const float* __restrict__ w_sr, const float* __restrict__ b_sr,
    const float* __restrict__ ln_g, const float* __restrict__ ln_b,
    const float* __restrict__ wqkv, u16* __restrict__ xa16, u16* __restrict__ WT,
    float* __restrict__ Z)
{
  const int blk = blockIdx.x;

  if (blk >= 4204) {                    // ---- zero S+ctx: 602112 B total ----
    int off = (blk - 4204) * 1536 + ((int)threadIdx.x << 2);
    const f4 zz = {0.f, 0.f, 0.f, 0.f};
    *(f4*)(Z + off) = zz;
    return;
  }

  if (blk >= 4096) {                    // ---- WT[col][k] = bf16(wqkv[k][col]) ----
    const int pb = blk - 4096;
    const int cg = pb % 18, kg = pb / 18;
    const int c0 = cg << 6, k0 = kg << 6;
    const int tid = threadIdx.x;
    __shared__ u16 t[64][72];
    if (tid < 256) {
#pragma unroll
      for (int i = 0; i < 4; i++) {
        int idx = tid + (i << 8);
        int r = idx >> 4, c4 = (idx & 15) << 2;
        f4 v = *(const f4*)(wqkv + (size_t)(k0 + r) * 1152 + c0 + c4);
#pragma unroll
        for (int j = 0; j < 4; j++) t[c4 + j][r] = f2bf(v[j]);
      }
    }
    __syncthreads();
    if (tid < 256) {
#pragma unroll
      for (int i = 0; i < 2; i++) {
        int idx = tid + (i << 8);
        int c = idx >> 3, j = (idx & 7) << 3;
        *(u16x8*)(WT + (size_t)(c0 + c) * 384 + k0 + j) = *(const u16x8*)&t[c][j];
      }
    }
    return;
  }

  // ---- conv path ----
  const int b = blk >> 9;
  const int hh = (blk >> 3) & 63;
  const int ww0 = (blk & 7) << 3;
  const int c = threadIdx.x;

  float wgt[9];
#pragma unroll
  for (int i = 0; i < 9; i++) wgt[i] = w_sr[c * 9 + i];
  const float lg = ln_g[c], lb = ln_b[c];
  const float bias = b_sr[c];

  float rowv[3][10];
#pragma unroll
  for (int r = 0; r < 3; r++) {
    int y = hh + r - 1;
    bool yok = (unsigned)y < 64u;
#pragma unroll
    for (int j = 0; j < 10; j++) {
      int xx = ww0 + j - 1;
      bool ok = yok && ((unsigned)xx < 64u);
      rowv[r][j] = ok ? x[((size_t)((b << 12) + (y << 6) + xx)) * CC + c] : 0.f;
    }
  }

  float acc[8];
#pragma unroll
  for (int p = 0; p < 8; p++) {
    float a = bias;
#pragma unroll
    for (int r = 0; r < 3; r++)
#pragma unroll
      for (int j = 0; j < 3; j++)
        a += rowv[r][p + j] * wgt[r * 3 + j];
    acc[p] = a;
  }

  __shared__ float ls1[6][8], ls2[6][8], mb[2][8];
  const int wid = threadIdx.x >> 6, lane = threadIdx.x & 63;
#pragma unroll
  for (int p = 0; p < 8; p++) {
    float s1 = acc[p], s2 = acc[p] * acc[p];
#pragma unroll
    for (int o = 32; o > 0; o >>= 1) { s1 += __shfl_down(s1, o); s2 += __shfl_down(s2, o); }
    if (lane == 0) { ls1[wid][p] = s1; ls2[wid][p] = s2; }
  }
  __syncthreads();
  if (threadIdx.x < 8) {
    int p = threadIdx.x;
    float a = 0.f, q = 0.f;
#pragma unroll
    for (int i = 0; i < 6; i++) { a += ls1[i][p]; q += ls2[i][p]; }
    float mean = a * (1.0f / CC);
    float var  = q * (1.0f / CC) - mean * mean;
    mb[0][p] = mean; mb[1][p] = rsqrtf(var + 1e-5f);
  }
  __syncthreads();
#pragma unroll
  for (int p = 0; p < 8; p++) {
    float xn = (acc[p] - mb[0][p]) * mb[1][p] * lg + lb;
    float g  = 0.5f * xn * (1.0f + erff(xn * 0.70710678118654752f));
    size_t pix = (size_t)(b << 12) + (hh << 6) + ww0 + p;
    xa16[pix * CC + c] = f2bf(rowv[1][p + 1] + g);
  }
}

// ---------------- Kernel B: merged qkv GEMM, XCD-coherent interleaved grid ----------------------
// bid = 24*G + g*8 + j  ->  rt = 8*G + j, g = (bid%24)>>3.  The 3 g-passes of rowtile rt are
// 8 & 16 bids apart (temporally adjacent) AND congruent mod 8 (same XCD round-robin slot) ->
// the A-panel is fetched from HBM once and served from that XCD's L2 for the other two passes.
// g=0: k (softmax -> K16T), g=1: v (-> V16T), g=2: q (exp -> P16 + S atomics).
// Async template + counted vmcnt + raw s_barrier (next-step DMAs survive the barrier).
__global__ __launch_bounds__(512) void k_qkv(
    const u16* __restrict__ xa16, const u16* __restrict__ WT, float* __restrict__ S,
    u16* __restrict__ K16T, u16* __restrict__ V16T, u16* __restrict__ P16)
{
  const int bid = blockIdx.x;           // 0..1535 = 24 * 64
  const int G   = bid / 24;
  const int w24 = bid - G * 24;
  const int g   = w24 >> 3;             // 0=k, 1=v, 2=q
  const int rt  = (G << 3) + (w24 & 7); // rowtile of 64
  const int b  = rt >> 6;
  const int n0 = rt << 6;
  const int tid = threadIdx.x;
  const int wv = tid >> 6, lane = tid & 63, l15 = lane & 15, quad = lane >> 4;
  const int wc = wv;

  __shared__ __attribute__((aligned(16))) u16 lA[2][64][32];
  __shared__ __attribute__((aligned(16))) u16 lB[2][384][32];

  const u16* Bbase = WT + (size_t)((g == 2) ? 0 : (384 + g * 384)) * 384;
  const int sw8 = (quad ^ ((l15 >> 1) & 3)) << 3;

  floatx4 acc[12];
  const floatx4 z = {0.f, 0.f, 0.f, 0.f};
#pragma unroll
  for (int i = 0; i < 12; i++) acc[i] = z;

  auto stage = [&](int bi, int k0) {
    if (wv < 4) {
      int cl = (wv << 4) + (lane >> 2);
      int sc = ((lane & 3) ^ ((cl >> 1) & 3)) << 3;
      __builtin_amdgcn_global_load_lds((gu32*)(xa16 + (size_t)(n0 + cl) * 384 + k0 + sc),
                                       (lu32*)&lA[bi][wv << 4][0], 16, 0, 0);
    }
#pragma unroll
    for (int i = 0; i < 3; i++) {
      int j = wv * 3 + i;
      int cl = (j << 4) + (lane >> 2);
      int sc = ((lane & 3) ^ ((cl >> 1) & 3)) << 3;
      __builtin_amdgcn_global_load_lds((gu32*)(Bbase + (size_t)cl * 384 + k0 + sc),
                                       (lu32*)&lB[bi][j << 4][0], 16, 0, 0);
    }
  };

  stage(0, 0);

  for (int t = 0; t < 12; t++) {
    const int cur = t & 1;
    if (t < 11) {
      stage(cur ^ 1, (t + 1) << 5);
      // wait for cur's DMAs (ours); leave the just-issued nxt DMAs in flight
      if (wv < 4) asm volatile("s_waitcnt vmcnt(4)" ::: "memory");
      else        asm volatile("s_waitcnt vmcnt(3)" ::: "memory");
    } else {
      asm volatile("s_waitcnt vmcnt(0)" ::: "memory");
    }
    __builtin_amdgcn_s_barrier();       // all waves' cur DMAs landed; nxt stays in flight
    short8 af[4], bf[3];
#pragma unroll
    for (int mi = 0; mi < 4; mi++) af[mi] = *(const short8*)&lA[cur][(mi << 4) + l15][sw8];
#pragma unroll
    for (int ni = 0; ni < 3; ni++) bf[ni] = *(const short8*)&lB[cur][wc * 48 + (ni << 4) + l15][sw8];
#pragma unroll
    for (int mi = 0; mi < 4; mi++)
#pragma unroll
      for (int ni = 0; ni < 3; ni++)
        acc[mi * 3 + ni] = __builtin_amdgcn_mfma_f32_16x16x32_bf16(af[mi], bf[ni], acc[mi * 3 + ni], 0, 0, 0);
    __builtin_amdgcn_s_barrier();       // reads of cur done before anyone re-stages it
  }

  if (g == 0) {
    // per-row softmax over this wave's head (48 cols = 3 regs x 16 l15 lanes)
#pragma unroll
    for (int mi = 0; mi < 4; mi++)
#pragma unroll
      for (int rr = 0; rr < 4; rr++) {
        float x0 = acc[mi * 3 + 0][rr], x1 = acc[mi * 3 + 1][rr], x2 = acc[mi * 3 + 2][rr];
        float m = fmaxf(fmaxf(x0, x1), x2);
#pragma unroll
        for (int o = 8; o >= 1; o >>= 1) m = fmaxf(m, __shfl_xor(m, o));
        float e0 = expf(x0 - m), e1 = expf(x1 - m), e2 = expf(x2 - m);
        float s = e0 + e1 + e2;
#pragma unroll
        for (int o = 8; o >= 1; o >>= 1) s += __shfl_xor(s, o);
        float inv = 1.0f / s;
        acc[mi * 3 + 0][rr] = e0 * inv; acc[mi * 3 + 1][rr] = e1 * inv; acc[mi * 3 + 2][rr] = e2 * inv;
      }
  }

  if (g == 2) {
    // q epilogue: exp -> P16 + column sums
#pragma unroll
    for (int ni = 0; ni < 3; ni++) {
      int col = wc * 48 + (ni << 4) + l15;
      float s = 0.f;
#pragma unroll
      for (int mi = 0; mi < 4; mi++) {
        int rowb = n0 + (mi << 4) + (quad << 2);
        float e0 = expf(acc[mi * 3 + ni][0]), e1 = expf(acc[mi * 3 + ni][1]);
        float e2 = expf(acc[mi * 3 + ni][2]), e3 = expf(acc[mi * 3 + ni][3]);
        P16[(size_t)(rowb + 0) * 384 + col] = f2bf(e0);
        P16[(size_t)(rowb + 1) * 384 + col] = f2bf(e1);
        P16[(size_t)(rowb + 2) * 384 + col] = f2bf(e2);
        P16[(size_t)(rowb + 3) * 384 + col] = f2bf(e3);
        s += e0 + e1 + e2 + e3;
      }
      s += __shfl_down(s, 32);
      s += __shfl_down(s, 16);
      if (lane < 16) atomicAdd(&S[b * 384 + wc * 48 + (ni << 4) + lane], s);
    }
  } else {
    u16* dst = g ? V16T : K16T;
    const int nl = ((rt & 63) << 6) + (quad << 2);
#pragma unroll
    for (int mi = 0; mi < 4; mi++)
#pragma unroll
      for (int ni = 0; ni < 3; ni++) {
        int hd = wc * 48 + (ni << 4) + l15;
        u16x4 v4 = { f2bf(acc[mi * 3 + ni][0]), f2bf(acc[mi * 3 + ni][1]),
                     f2bf(acc[mi * 3 + ni][2]), f2bf(acc[mi * 3 + ni][3]) };
        *(u16x4*)(dst + ((size_t)b * 384 + hd) * 4096 + nl + (mi << 4)) = v4;
      }
  }
}

// ---------------- Kernel C: ctx[bh,48,48] += ksm^T @ v over 256-row n-chunks (MFMA) -------------
__global__ __launch_bounds__(256) void k_ctx(
    const u16* __restrict__ K16T, const u16* __restrict__ V16T, float* __restrict__ ctx)
{
  const int bh = blockIdx.x;           // 64
  const int b = bh >> 3, h = bh & 7;
  const int n0 = blockIdx.y << 8;      // chunk of 256 n
  const int tid = threadIdx.x;
  const int wv = tid >> 6, lane = tid & 63, l15 = lane & 15, quad = lane >> 4;

  __shared__ __attribute__((aligned(16))) char smem[50688];
  u16 (*lkT)[264] = (u16(*)[264])smem;             // 48 x 264 (ksm^T: [d][n])
  u16 (*lvT)[264] = (u16(*)[264])(smem + 25344);   // 48 x 264 (v^T:   [e][n])
  float (*pctx)[2304] = (float(*)[2304])smem;      // 4 x 2304 (overlaps, used after barrier)

#pragma unroll
  for (int i = 0; i < 6; i++) {
    int idx = tid + (i << 8);          // 0..1535
    int d = idx >> 5, c8 = (idx & 31) << 3;
    *(u16x8*)&lkT[d][c8] = *(const u16x8*)(K16T + ((size_t)b * 384 + h * 48 + d) * 4096 + n0 + c8);
    *(u16x8*)&lvT[d][c8] = *(const u16x8*)(V16T + ((size_t)b * 384 + h * 48 + d) * 4096 + n0 + c8);
  }
  __syncthreads();

  floatx4 c2[9];
  const floatx4 z = {0.f, 0.f, 0.f, 0.f};
#pragma unroll
  for (int i = 0; i < 9; i++) c2[i] = z;
#pragma unroll
  for (int kk2 = 0; kk2 < 2; kk2++) {
    int rb = (wv << 6) + (kk2 << 5) + (quad << 3);
    short8 ak[3], av[3];
#pragma unroll
    for (int t = 0; t < 3; t++) {
      ak[t] = *(const short8*)&lkT[(t << 4) + l15][rb];
      av[t] = *(const short8*)&lvT[(t << 4) + l15][rb];
    }
#pragma unroll
    for (int dt = 0; dt < 3; dt++)
#pragma unroll
      for (int et = 0; et < 3; et++)
        c2[dt * 3 + et] = __builtin_amdgcn_mfma_f32_16x16x32_bf16(ak[dt], av[et], c2[dt * 3 + et], 0, 0, 0);
  }
  __syncthreads();   // done reading lkT/lvT; smem reused as pctx

#pragma unroll
  for (int dt = 0; dt < 3; dt++)
#pragma unroll
    for (int et = 0; et < 3; et++)
#pragma unroll
      for (int rr = 0; rr < 4; rr++) {
        int d = (dt << 4) + (quad << 2) + rr;
        int e = (et << 4) + l15;
        pctx[wv][d * 48 + e] = c2[dt * 3 + et][rr];
      }
  __syncthreads();
#pragma unroll
  for (int i = 0; i < 9; i++) {
    int cell = tid + (i << 8);
    float s = pctx[0][cell] + pctx[1][cell] + pctx[2][cell] + pctx[3][cell];
    atomicAdd(&ctx[(size_t)bh * 2304 + cell], s);
  }
}

// ---------------- Kernel D: W2T[b, c, h*48+d] = sum_e (ctx[bh,d,e]/S[..]) * wp[h*48+e, c] -------
__global__ __launch_bounds__(256) void k_w2(
    const float* __restrict__ ctx, const float* __restrict__ S,
    const float* __restrict__ wp, u16* __restrict__ W2T)
{
  const int bh = blockIdx.x;   // 64
  const int b = bh >> 3, h = bh & 7;
  const int c0 = blockIdx.y << 7;
  const int tid = threadIdx.x;
  __shared__ float rs[48];
  __shared__ float c2[48][48];
  __shared__ float lwp[48][128];
  __shared__ u16 tr[128][48];
  if (tid < 48) rs[tid] = 1.0f / S[b * 384 + h * 48 + tid];
  __syncthreads();
#pragma unroll
  for (int i = 0; i < 9; i++) {
    int cell = tid + (i << 8);
    int d = cell / 48, e = cell - d * 48;
    c2[d][e] = ctx[(size_t)bh * 2304 + cell] * rs[d];
  }
#pragma unroll
  for (int i = 0; i < 24; i++) {
    int idx = tid + (i << 8);            // 0..6143
    int e = idx >> 7, c = idx & 127;
    lwp[e][c] = wp[(size_t)(h * 48 + e) * 384 + c0 + c];
  }
  __syncthreads();
  const int c = tid & 127;
  const int dbase = tid >> 7;            // 0 or 1
#pragma unroll
  for (int it = 0; it < 24; it++) {
    int d = (it << 1) + dbase;
    float s = 0.f;
#pragma unroll
    for (int e = 0; e < 48; e++) s += c2[d][e] * lwp[e][c];
    tr[c][d] = f2bf(s);
  }
  __syncthreads();
  const int cc = tid >> 1, half = tid & 1;
#pragma unroll
  for (int i = 0; i < 3; i++) {
    u16x8 v = *(const u16x8*)&tr[cc][half * 24 + (i << 3)];
    *(u16x8*)(W2T + ((size_t)b * 384 + c0 + cc) * 384 + h * 48 + half * 24 + (i << 3)) = v;
  }
}

// ---------------- Kernel E: out = P @ W2_b + bias + x  (async template + counted vmcnt) ---------
__global__ __launch_bounds__(512) void k_qproj(
    const u16* __restrict__ P16, const u16* __restrict__ W2T,
    const float* __restrict__ bias, const float* __restrict__ x, float* __restrict__ out)
{
  const int bm = blockIdx.x;            // 512 rowtiles of 64
  const int b = bm >> 6;
  const int n0 = bm << 6;
  const int tid = threadIdx.x;
  const int wv = tid >> 6, lane = tid & 63, l15 = lane & 15, quad = lane >> 4;
  const int wc = wv;

  __shared__ __attribute__((aligned(16))) u16 lA[2][64][32];
  __shared__ __attribute__((aligned(16))) u16 lB[2][384][32];

  const u16* Bbase = W2T + (size_t)b * 384 * 384;
  const int sw8 = (quad ^ ((l15 >> 1) & 3)) << 3;

  floatx4 acc[12];
  const floatx4 z = {0.f, 0.f, 0.f, 0.f};
#pragma unroll
  for (int i = 0; i < 12; i++) acc[i] = z;

  auto stage = [&](int bi, int k0) {
    if (wv < 4) {
      int cl = (wv << 4) + (lane >> 2);
      int sc = ((lane & 3) ^ ((cl >> 1) & 3)) << 3;
      __builtin_amdgcn_global_load_lds((gu32*)(P16 + (size_t)(n0 + cl) * 384 + k0 + sc),
                                       (lu32*)&lA[bi][wv << 4][0], 16, 0, 0);
    }
#pragma unroll
    for (int i = 0; i < 3; i++) {
      int j = wv * 3 + i;
      int cl = (j << 4) + (lane >> 2);
      int sc = ((lane & 3) ^ ((cl >> 1) & 3)) << 3;
      __builtin_amdgcn_global_load_lds((gu32*)(Bbase + (size_t)cl * 384 + k0 + sc),
                                       (lu32*)&lB[bi][j << 4][0], 16, 0, 0);
    }
  };

  stage(0, 0);

  for (int t = 0; t < 12; t++) {
    const int cur = t & 1;
    if (t < 11) {
      stage(cur ^ 1, (t + 1) << 5);
      if (wv < 4) asm volatile("s_waitcnt vmcnt(4)" ::: "memory");
      else        asm volatile("s_waitcnt vmcnt(3)" ::: "memory");
    } else {
      asm volatile("s_waitcnt vmcnt(0)" ::: "memory");
    }
    __builtin_amdgcn_s_barrier();
    short8 af[4], bf[3];
#pragma unroll
    for (int mi = 0; mi < 4; mi++) af[mi] = *(const short8*)&lA[cur][(mi << 4) + l15][sw8];
#pragma unroll
    for (int ni = 0; ni < 3; ni++) bf[ni] = *(const short8*)&lB[cur][wc * 48 + (ni << 4) + l15][sw8];
#pragma unroll
    for (int mi = 0; mi < 4; mi++)
#pragma unroll
      for (int ni = 0; ni < 3; ni++)
        acc[mi * 3 + ni] = __builtin_amdgcn_mfma_f32_16x16x32_bf16(af[mi], bf[ni], acc[mi * 3 + ni], 0, 0, 0);
    __builtin_amdgcn_s_barrier();
  }

#pragma unroll
  for (int ni = 0; ni < 3; ni++) {
    int col = wc * 48 + (ni << 4) + l15;
    float bc = bias[col];
#pragma unroll
    for (int mi = 0; mi < 4; mi++) {
#pragma unroll
      for (int rr = 0; rr < 4; rr++) {
        int row = n0 + (mi << 4) + (quad << 2) + rr;
        out[(size_t)row * 384 + col] = acc[mi * 3 + ni][rr] + bc + x[(size_t)row * 384 + col];
      }
    }
  }
}

extern "C" void kernel_launch(void* const* d_in, const int* in_sizes, int n_in,
                              void* d_out, int out_size, void* d_ws, size_t ws_size,
                              hipStream_t stream)
{
  const float* x      = (const float*)d_in[0];
  const float* w_sr   = (const float*)d_in[1];
  const float* b_sr   = (const float*)d_in[2];
  const float* ln_g   = (const float*)d_in[3];
  const float* ln_b   = (const float*)d_in[4];
  const float* w_qkv  = (const float*)d_in[5];
  const float* w_proj = (const float*)d_in[6];
  const float* b_proj = (const float*)d_in[7];
  float* out = (float*)d_out;

  // ws layout — total 54,177,792 bytes (~54.2 MB):
  //   [0,        12288)     S    [8][384] f32      (zeroed by k_pre)
  //   [12288,    602112)    ctx  [64][48][48] f32  (zeroed by k_pre)
  //   [602112,   1486848)   WT   [1152][384] bf16
  //   [1486848,  3846144)   W2T  [8][384][384] bf16
  //   [3846144,  29011968)  xa16 [32768][384] bf16
  //   [29011968, 54177792)  P16  [32768][384] bf16
  // d_out (50.3 MB) doubles as scratch for K16T+V16T (2 x 25.17 MB) until k_qproj writes it.
  float* S   = (float*)d_ws;
  float* ctx = (float*)((char*)d_ws + 12288);
  u16*   WT  = (u16*)((char*)d_ws + 602112);
  u16*   W2T = (u16*)((char*)d_ws + 1486848);
  u16*   xa16= (u16*)((char*)d_ws + 3846144);
  u16*   P16 = (u16*)((char*)d_ws + 29011968);
  u16*   K16T= (u16*)d_out;              // [8][384][4096] bf16
  u16*   V16T= (u16*)d_out + (size_t)8 * 384 * 4096;

  k_pre<<<4302, 384, 0, stream>>>(x, w_sr, b_sr, ln_g, ln_b, w_qkv, xa16, WT, (float*)d_ws);
  k_qkv<<<1536, 512, 0, stream>>>(xa16, WT, S, K16T, V16T, P16);
  k_ctx<<<dim3(64, 16), 256, 0, stream>>>(K16T, V16T, ctx);
  k_w2<<<dim3(64, 3), 256, 0, stream>>>(ctx, S, w_proj, W2T);
  k_qproj<<<512, 512, 0, stream>>>(P16, W2T, b_proj, x, out);
}